// Round 2
// baseline (658.845 us; speedup 1.0000x reference)
//
#include <hip/hip_runtime.h>
#include <hip/hip_bf16.h>

#define KK 5
constexpr int N0 = 78400;     // B*28*28
constexpr int E0 = 627200;    // N0*8
constexpr int N1 = 19600;     // B*14*14
constexpr int E1 = 156800;    // N1*8
constexpr int C1 = 32, C2 = 64;
constexpr int BSZ = 100;
constexpr int FC1_IN = 3136, FC1_OUT = 512, FC2_OUT = 10;

__device__ __forceinline__ void taps_of(const float* pseudo, int e,
                                        int& a00, int& a01, int& a10, int& a11,
                                        float& c00, float& c01, float& c10, float& c11) {
    float px = pseudo[2 * e] * (KK - 1);
    float py = pseudo[2 * e + 1] * (KK - 1);
    float kfx = floorf(px), kfy = floorf(py);
    float fx = px - kfx, fy = py - kfy;
    int k0x = min(max((int)kfx, 0), KK - 1);
    int k0y = min(max((int)kfy, 0), KK - 1);
    int k1x = min(k0x + 1, KK - 1), k1y = min(k0y + 1, KK - 1);
    a00 = k0x * KK + k0y; a01 = k0x * KK + k1y;
    a10 = k1x * KK + k0y; a11 = k1x * KK + k1y;
    float gx = 1.f - fx, gy = 1.f - fy;
    c00 = gx * gy; c01 = gx * fy; c10 = fx * gy; c11 = fx * fy;
}

// ---- conv1: per (edge, out-channel) scatter. Cin = 1. ----
__global__ void conv1_edges(const float* __restrict__ x, const float* __restrict__ pseudo,
                            const int* __restrict__ ei, const float* __restrict__ W1,
                            float* __restrict__ agg, float* __restrict__ deg) {
    int idx = blockIdx.x * blockDim.x + threadIdx.x;
    if (idx >= E0 * C1) return;
    int e = idx >> 5, o = idx & 31;
    int srcn = ei[e], dstn = ei[E0 + e];
    int a00, a01, a10, a11; float c00, c01, c10, c11;
    taps_of(pseudo, e, a00, a01, a10, a11, c00, c01, c10, c11);
    float w = c00 * W1[a00 * C1 + o] + c01 * W1[a01 * C1 + o] +
              c10 * W1[a10 * C1 + o] + c11 * W1[a11 * C1 + o];
    float val = x[srcn] * w;
    atomicAdd(&agg[dstn * C1 + o], val);
    if (o == 0) atomicAdd(&deg[dstn], 1.0f);
}

// ---- node1: mean + root + bias + ELU, in-place over agg ----
__global__ void node1(const float* __restrict__ x, const float* __restrict__ root,
                      const float* __restrict__ bias, const float* __restrict__ deg,
                      float* __restrict__ agg) {
    int idx = blockIdx.x * blockDim.x + threadIdx.x;
    if (idx >= N0 * C1) return;
    int n = idx >> 5, o = idx & 31;
    float v = agg[idx] / fmaxf(deg[n], 1.0f) + x[n] * root[o] + bias[o];
    agg[idx] = v > 0.f ? v : expm1f(v);
}

// ---- pool1: [100,28,28,32] -> [100,14,14,32] ----
__global__ void pool1(const float* __restrict__ h1, float* __restrict__ p1) {
    int idx = blockIdx.x * blockDim.x + threadIdx.x;
    if (idx >= N1 * C1) return;
    int o = idx & 31; int t = idx >> 5;
    int c = t % 14; int r = (t / 14) % 14; int b = t / 196;
    const float* base = h1 + (((b * 28 + 2 * r) * 28 + 2 * c) * C1 + o);
    float m = fmaxf(fmaxf(base[0], base[C1]),
                    fmaxf(base[28 * C1], base[28 * C1 + C1]));
    p1[idx] = m;
}

// ---- conv2: per (edge, out-channel), inner loop Cin=32, blend 4 taps of W2 ----
__global__ void conv2_edges(const float* __restrict__ p1, const float* __restrict__ pseudo,
                            const int* __restrict__ ei, const float* __restrict__ W2,
                            float* __restrict__ agg, float* __restrict__ deg) {
    int idx = blockIdx.x * blockDim.x + threadIdx.x;
    if (idx >= E1 * C2) return;
    int e = idx >> 6, o = idx & 63;
    int srcn = ei[e], dstn = ei[E1 + e];
    int a00, a01, a10, a11; float c00, c01, c10, c11;
    taps_of(pseudo, e, a00, a01, a10, a11, c00, c01, c10, c11);
    const float* w00 = W2 + a00 * C1 * C2 + o;
    const float* w01 = W2 + a01 * C1 * C2 + o;
    const float* w10 = W2 + a10 * C1 * C2 + o;
    const float* w11 = W2 + a11 * C1 * C2 + o;
    const float* xr = p1 + srcn * C1;
    float acc = 0.f;
#pragma unroll 8
    for (int i = 0; i < C1; i++) {
        float wi = c00 * w00[i * C2] + c01 * w01[i * C2] +
                   c10 * w10[i * C2] + c11 * w11[i * C2];
        acc += xr[i] * wi;
    }
    atomicAdd(&agg[dstn * C2 + o], acc);
    if (o == 0) atomicAdd(&deg[dstn], 1.0f);
}

// ---- node2: mean + x@root2 + bias + ELU, in-place over agg ----
__global__ void node2(const float* __restrict__ p1, const float* __restrict__ root2,
                      const float* __restrict__ bias, const float* __restrict__ deg,
                      float* __restrict__ agg) {
    int idx = blockIdx.x * blockDim.x + threadIdx.x;
    if (idx >= N1 * C2) return;
    int n = idx >> 6, o = idx & 63;
    float acc = agg[idx] / fmaxf(deg[n], 1.0f);
    const float* xr = p1 + n * C1;
#pragma unroll 8
    for (int i = 0; i < C1; i++) acc += xr[i] * root2[i * C2 + o];
    acc += bias[o];
    agg[idx] = acc > 0.f ? acc : expm1f(acc);
}

// ---- pool2: view [19600,64] as [25,28,28,64] -> [25,14,14,64] == [100,3136] ----
__global__ void pool2(const float* __restrict__ h2, float* __restrict__ p2) {
    int idx = blockIdx.x * blockDim.x + threadIdx.x;
    if (idx >= 25 * 14 * 14 * C2) return;
    int o = idx & 63; int t = idx >> 6;
    int c = t % 14; int r = (t / 14) % 14; int b = t / 196;
    const float* base = h2 + (((b * 28 + 2 * r) * 28 + 2 * c) * C2 + o);
    float m = fmaxf(fmaxf(base[0], base[C2]),
                    fmaxf(base[28 * C2], base[28 * C2 + C2]));
    p2[idx] = m;
}

// ---- fc1: [100,3136] @ [3136,512] + b, ELU ----
__global__ void fc1_kernel(const float* __restrict__ p2, const float* __restrict__ w,
                           const float* __restrict__ bias, float* __restrict__ z1) {
    int idx = blockIdx.x * blockDim.x + threadIdx.x;
    if (idx >= BSZ * FC1_OUT) return;
    int b = idx >> 9, j = idx & 511;
    const float* xr = p2 + b * FC1_IN;
    float acc = 0.f;
#pragma unroll 4
    for (int k = 0; k < FC1_IN; k++) acc += xr[k] * w[k * FC1_OUT + j];
    acc += bias[j];
    z1[idx] = acc > 0.f ? acc : expm1f(acc);
}

// ---- fc2: [100,512] @ [512,10] + b, ELU ----
__global__ void fc2_kernel(const float* __restrict__ z1, const float* __restrict__ w,
                           const float* __restrict__ bias, float* __restrict__ z2) {
    int idx = blockIdx.x * blockDim.x + threadIdx.x;
    if (idx >= BSZ * FC2_OUT) return;
    int b = idx / FC2_OUT, j = idx % FC2_OUT;
    const float* xr = z1 + b * 512;
    float acc = 0.f;
#pragma unroll 8
    for (int k = 0; k < 512; k++) acc += xr[k] * w[k * FC2_OUT + j];
    acc += bias[j];
    z2[idx] = acc > 0.f ? acc : expm1f(acc);
}

// ---- log_softmax over 10 classes ----
__global__ void lsm_kernel(const float* __restrict__ z2, float* __restrict__ out) {
    int b = blockIdx.x * blockDim.x + threadIdx.x;
    if (b >= BSZ) return;
    const float* r = z2 + b * FC2_OUT;
    float m = -1e30f;
    for (int j = 0; j < FC2_OUT; j++) m = fmaxf(m, r[j]);
    float s = 0.f;
    for (int j = 0; j < FC2_OUT; j++) s += expf(r[j] - m);
    float ls = logf(s) + m;
    for (int j = 0; j < FC2_OUT; j++) out[b * FC2_OUT + j] = r[j] - ls;
}

extern "C" void kernel_launch(void* const* d_in, const int* in_sizes, int n_in,
                              void* d_out, int out_size, void* d_ws, size_t ws_size,
                              hipStream_t stream) {
    const float* x     = (const float*)d_in[0];
    const float* ps0   = (const float*)d_in[1];
    const float* ps1   = (const float*)d_in[2];
    const float* W1    = (const float*)d_in[3];
    const float* root1 = (const float*)d_in[4];
    const float* b1    = (const float*)d_in[5];
    const float* W2    = (const float*)d_in[6];
    const float* root2 = (const float*)d_in[7];
    const float* b2v   = (const float*)d_in[8];
    const float* fc1w  = (const float*)d_in[9];
    const float* fc1b  = (const float*)d_in[10];
    const float* fc2w  = (const float*)d_in[11];
    const float* fc2b  = (const float*)d_in[12];
    const int*   ei0   = (const int*)d_in[13];
    const int*   ei1   = (const int*)d_in[14];

    float* ws = (float*)d_ws;
    float* agg1 = ws;                       // N0*C1 = 2,508,800
    float* deg1 = ws + 2508800;             // N0    =    78,400
    float* agg2 = ws + 2587200;             // N1*C2 = 1,254,400
    float* deg2 = ws + 3841600;             // N1    =    19,600
    float* p1   = ws + 3861200;             // N1*C1 =   627,200
    float* p2   = ws + 4488400;             //          313,600
    float* z1   = ws + 4802000;             //           51,200
    float* z2   = ws + 4853200;             //            1,000

    // zero the aggregation buffers (agg1|deg1|agg2|deg2 are contiguous)
    hipMemsetAsync(ws, 0, (size_t)3861200 * sizeof(float), stream);

    conv1_edges<<<(E0 * C1 + 255) / 256, 256, 0, stream>>>(x, ps0, ei0, W1, agg1, deg1);
    node1<<<(N0 * C1 + 255) / 256, 256, 0, stream>>>(x, root1, b1, deg1, agg1);
    pool1<<<(N1 * C1 + 255) / 256, 256, 0, stream>>>(agg1, p1);
    conv2_edges<<<(E1 * C2 + 255) / 256, 256, 0, stream>>>(p1, ps1, ei1, W2, agg2, deg2);
    node2<<<(N1 * C2 + 255) / 256, 256, 0, stream>>>(p1, root2, b2v, deg2, agg2);
    pool2<<<(25 * 14 * 14 * C2 + 255) / 256, 256, 0, stream>>>(agg2, p2);
    fc1_kernel<<<(BSZ * FC1_OUT + 255) / 256, 256, 0, stream>>>(p2, fc1w, fc1b, z1);
    fc2_kernel<<<(BSZ * FC2_OUT + 255) / 256, 256, 0, stream>>>(z1, fc2w, fc2b, z2);
    lsm_kernel<<<1, 128, 0, stream>>>(z2, (float*)d_out);
}

// Round 3
// 536.138 us; speedup vs baseline: 1.2289x; 1.2289x over previous
//
#include <hip/hip_runtime.h>
#include <hip/hip_bf16.h>

#define KK 5
constexpr int N0 = 78400;     // B*28*28
constexpr int E0 = 627200;    // N0*8
constexpr int N1 = 19600;     // B*14*14
constexpr int E1 = 156800;    // N1*8
constexpr int C1 = 32, C2 = 64;
constexpr int BSZ = 100;
constexpr int FC1_IN = 3136, FC1_OUT = 512;

__device__ __forceinline__ void taps_of(const float* pseudo, int e,
                                        int& a00, int& a01, int& a10, int& a11,
                                        float& c00, float& c01, float& c10, float& c11) {
    float px = pseudo[2 * e] * (KK - 1);
    float py = pseudo[2 * e + 1] * (KK - 1);
    float kfx = floorf(px), kfy = floorf(py);
    float fx = px - kfx, fy = py - kfy;
    int k0x = min(max((int)kfx, 0), KK - 1);
    int k0y = min(max((int)kfy, 0), KK - 1);
    int k1x = min(k0x + 1, KK - 1), k1y = min(k0y + 1, KK - 1);
    a00 = k0x * KK + k0y; a01 = k0x * KK + k1y;
    a10 = k1x * KK + k0y; a11 = k1x * KK + k1y;
    float gx = 1.f - fx, gy = 1.f - fy;
    c00 = gx * gy; c01 = gx * fy; c10 = fx * gy; c11 = fx * fy;
}

// ---- conv1 scatter: per edge, scatter x[src]*coeff into tap-space S[dst, 25] ----
__global__ void conv1_scatter(const float* __restrict__ x, const float* __restrict__ pseudo,
                              const int* __restrict__ ei,
                              float* __restrict__ S, float* __restrict__ deg) {
    int e = blockIdx.x * blockDim.x + threadIdx.x;
    if (e >= E0) return;
    int srcn = ei[e], dstn = ei[E0 + e];
    int a00, a01, a10, a11; float c00, c01, c10, c11;
    taps_of(pseudo, e, a00, a01, a10, a11, c00, c01, c10, c11);
    float xv = x[srcn];
    float* Sr = S + dstn * 32;
    atomicAdd(&Sr[a00], c00 * xv);
    atomicAdd(&Sr[a01], c01 * xv);
    atomicAdd(&Sr[a10], c10 * xv);
    atomicAdd(&Sr[a11], c11 * xv);
    atomicAdd(&deg[dstn], 1.0f);
}

// ---- node1: h1[n,o] = ELU( (S[n,:] @ W1[:,o]) / deg + x[n]*root[o] + bias[o] ) ----
__global__ void node1(const float* __restrict__ x, const float* __restrict__ W1,
                      const float* __restrict__ root, const float* __restrict__ bias,
                      const float* __restrict__ deg, const float* __restrict__ S,
                      float* __restrict__ h1) {
    int idx = blockIdx.x * blockDim.x + threadIdx.x;
    if (idx >= N0 * C1) return;
    int n = idx >> 5, o = idx & 31;
    const float* Sr = S + n * 32;
    float acc = 0.f;
#pragma unroll
    for (int k = 0; k < 25; k++) acc += Sr[k] * W1[k * C1 + o];
    float v = acc / fmaxf(deg[n], 1.0f) + x[n] * root[o] + bias[o];
    h1[idx] = v > 0.f ? v : expm1f(v);
}

// ---- pool1: [100,28,28,32] -> [100,14,14,32] ----
__global__ void pool1(const float* __restrict__ h1, float* __restrict__ p1) {
    int idx = blockIdx.x * blockDim.x + threadIdx.x;
    if (idx >= N1 * C1) return;
    int o = idx & 31; int t = idx >> 5;
    int c = t % 14; int r = (t / 14) % 14; int b = t / 196;
    const float* base = h1 + (((b * 28 + 2 * r) * 28 + 2 * c) * C1 + o);
    float m = fmaxf(fmaxf(base[0], base[C1]),
                    fmaxf(base[28 * C1], base[28 * C1 + C1]));
    p1[idx] = m;
}

// ---- conv2: per (edge, out-channel), inner loop Cin=32, blend 4 taps of W2 ----
__global__ void conv2_edges(const float* __restrict__ p1, const float* __restrict__ pseudo,
                            const int* __restrict__ ei, const float* __restrict__ W2,
                            float* __restrict__ agg, float* __restrict__ deg) {
    int idx = blockIdx.x * blockDim.x + threadIdx.x;
    if (idx >= E1 * C2) return;
    int e = idx >> 6, o = idx & 63;
    int srcn = ei[e], dstn = ei[E1 + e];
    int a00, a01, a10, a11; float c00, c01, c10, c11;
    taps_of(pseudo, e, a00, a01, a10, a11, c00, c01, c10, c11);
    const float* w00 = W2 + a00 * C1 * C2 + o;
    const float* w01 = W2 + a01 * C1 * C2 + o;
    const float* w10 = W2 + a10 * C1 * C2 + o;
    const float* w11 = W2 + a11 * C1 * C2 + o;
    const float* xr = p1 + srcn * C1;
    float acc = 0.f;
#pragma unroll 8
    for (int i = 0; i < C1; i++) {
        float wi = c00 * w00[i * C2] + c01 * w01[i * C2] +
                   c10 * w10[i * C2] + c11 * w11[i * C2];
        acc += xr[i] * wi;
    }
    atomicAdd(&agg[dstn * C2 + o], acc);
    if (o == 0) atomicAdd(&deg[dstn], 1.0f);
}

// ---- node2: mean + x@root2 + bias + ELU, in-place over agg ----
__global__ void node2(const float* __restrict__ p1, const float* __restrict__ root2,
                      const float* __restrict__ bias, const float* __restrict__ deg,
                      float* __restrict__ agg) {
    int idx = blockIdx.x * blockDim.x + threadIdx.x;
    if (idx >= N1 * C2) return;
    int n = idx >> 6, o = idx & 63;
    float acc = agg[idx] / fmaxf(deg[n], 1.0f);
    const float* xr = p1 + n * C1;
#pragma unroll 8
    for (int i = 0; i < C1; i++) acc += xr[i] * root2[i * C2 + o];
    acc += bias[o];
    agg[idx] = acc > 0.f ? acc : expm1f(acc);
}

// ---- pool2: view [19600,64] as [25,28,28,64] -> [25,14,14,64] == [100,3136] ----
__global__ void pool2(const float* __restrict__ h2, float* __restrict__ p2) {
    int idx = blockIdx.x * blockDim.x + threadIdx.x;
    if (idx >= 25 * 14 * 14 * C2) return;
    int o = idx & 63; int t = idx >> 6;
    int c = t % 14; int r = (t / 14) % 14; int b = t / 196;
    const float* base = h2 + (((b * 28 + 2 * r) * 28 + 2 * c) * C2 + o);
    float m = fmaxf(fmaxf(base[0], base[C2]),
                    fmaxf(base[28 * C2], base[28 * C2 + C2]));
    p2[idx] = m;
}

// ---- fc1 split-K: grid (25 bgroups, 8 jtiles, 4 kz); block 256 = 64 j x 4 ks ----
// z1[b, j] += sum over this block's K-slice; z1 pre-zeroed; bias+ELU deferred to fc2.
__global__ void fc1_splitk(const float* __restrict__ p2, const float* __restrict__ w,
                           float* __restrict__ z1) {
    int bg = blockIdx.x;           // 0..24  (4 batch rows each)
    int jt = blockIdx.y;           // 0..7   (64 outputs each)
    int kz = blockIdx.z;           // 0..3   (784 k each)
    int t = threadIdx.x;
    int j = (jt << 6) + (t & 63);
    int ks = t >> 6;               // 0..3 -> 196 k each
    int k0 = kz * 784 + ks * 196;
    const float* x0 = p2 + (bg * 4 + 0) * FC1_IN;
    const float* x1 = p2 + (bg * 4 + 1) * FC1_IN;
    const float* x2 = p2 + (bg * 4 + 2) * FC1_IN;
    const float* x3 = p2 + (bg * 4 + 3) * FC1_IN;
    const float* wp = w + j;
    float a0 = 0.f, a1 = 0.f, a2 = 0.f, a3 = 0.f;
#pragma unroll 4
    for (int kk = 0; kk < 196; kk++) {
        int k = k0 + kk;
        float wv = wp[k * FC1_OUT];
        a0 += x0[k] * wv; a1 += x1[k] * wv;
        a2 += x2[k] * wv; a3 += x3[k] * wv;
    }
    atomicAdd(&z1[(bg * 4 + 0) * FC1_OUT + j], a0);
    atomicAdd(&z1[(bg * 4 + 1) * FC1_OUT + j], a1);
    atomicAdd(&z1[(bg * 4 + 2) * FC1_OUT + j], a2);
    atomicAdd(&z1[(bg * 4 + 3) * FC1_OUT + j], a3);
}

// ---- fc2 + log_softmax fused; applies fc1 bias+ELU inline. block=640 (10 waves) ----
__global__ void fc2_lsm(const float* __restrict__ z1, const float* __restrict__ fc1b,
                        const float* __restrict__ w, const float* __restrict__ fc2b,
                        float* __restrict__ out) {
    int b = blockIdx.x;
    int t = threadIdx.x;
    int wv = t >> 6;               // wave id = output class j (0..9)
    int lane = t & 63;
    const float* zr = z1 + b * 512;
    float acc = 0.f;
#pragma unroll
    for (int m = 0; m < 8; m++) {
        int k = lane * 8 + m;
        float xv = zr[k] + fc1b[k];
        xv = xv > 0.f ? xv : expm1f(xv);
        acc += xv * w[k * 10 + wv];
    }
#pragma unroll
    for (int off = 32; off > 0; off >>= 1) acc += __shfl_down(acc, off);
    __shared__ float zs[10];
    if (lane == 0) {
        float z = acc + fc2b[wv];
        zs[wv] = z > 0.f ? z : expm1f(z);
    }
    __syncthreads();
    if (t < 10) {
        float m = -1e30f;
        for (int jj = 0; jj < 10; jj++) m = fmaxf(m, zs[jj]);
        float s = 0.f;
        for (int jj = 0; jj < 10; jj++) s += expf(zs[jj] - m);
        out[b * 10 + t] = zs[t] - m - logf(s);
    }
}

extern "C" void kernel_launch(void* const* d_in, const int* in_sizes, int n_in,
                              void* d_out, int out_size, void* d_ws, size_t ws_size,
                              hipStream_t stream) {
    const float* x     = (const float*)d_in[0];
    const float* ps0   = (const float*)d_in[1];
    const float* ps1   = (const float*)d_in[2];
    const float* W1    = (const float*)d_in[3];
    const float* root1 = (const float*)d_in[4];
    const float* b1    = (const float*)d_in[5];
    const float* W2    = (const float*)d_in[6];
    const float* root2 = (const float*)d_in[7];
    const float* b2v   = (const float*)d_in[8];
    const float* fc1w  = (const float*)d_in[9];
    const float* fc1b  = (const float*)d_in[10];
    const float* fc2w  = (const float*)d_in[11];
    const float* fc2b  = (const float*)d_in[12];
    const int*   ei0   = (const int*)d_in[13];
    const int*   ei1   = (const int*)d_in[14];

    float* ws = (float*)d_ws;
    float* S1   = ws;                       // 78400*32 = 2,508,800  (only 25/32 cols used)
    float* deg1 = ws + 2508800;             //    78,400
    float* agg2 = ws + 2587200;             // 1,254,400
    float* deg2 = ws + 3841600;             //    19,600
    float* z1   = ws + 3861200;             //    51,200
    // ---- memset boundary: 3,912,400 floats ----
    float* h1   = ws + 3912400;             // 2,508,800
    float* p1   = ws + 6421200;             //   627,200
    float* p2   = ws + 7048400;             //   313,600
    // high water: 7,362,000 floats = 29.4 MB

    hipMemsetAsync(ws, 0, (size_t)3912400 * sizeof(float), stream);

    conv1_scatter<<<(E0 + 255) / 256, 256, 0, stream>>>(x, ps0, ei0, S1, deg1);
    node1<<<(N0 * C1 + 255) / 256, 256, 0, stream>>>(x, W1, root1, b1, deg1, S1, h1);
    pool1<<<(N1 * C1 + 255) / 256, 256, 0, stream>>>(h1, p1);
    conv2_edges<<<(E1 * C2 + 255) / 256, 256, 0, stream>>>(p1, ps1, ei1, W2, agg2, deg2);
    node2<<<(N1 * C2 + 255) / 256, 256, 0, stream>>>(p1, root2, b2v, deg2, agg2);
    pool2<<<(25 * 14 * 14 * C2 + 255) / 256, 256, 0, stream>>>(agg2, p2);
    fc1_splitk<<<dim3(25, 8, 4), 256, 0, stream>>>(p2, fc1w, z1);
    fc2_lsm<<<BSZ, 640, 0, stream>>>(z1, fc1b, fc2w, fc2b, (float*)d_out);
}

// Round 4
// 443.540 us; speedup vs baseline: 1.4854x; 1.2088x over previous
//
#include <hip/hip_runtime.h>
#include <hip/hip_bf16.h>

#define KK 5
constexpr int N0 = 78400;     // B*28*28
constexpr int E0 = 627200;    // N0*8
constexpr int N1 = 19600;     // B*14*14
constexpr int E1 = 156800;    // N1*8
constexpr int C1 = 32, C2 = 64;
constexpr int BSZ = 100;
constexpr int FC1_IN = 3136, FC1_OUT = 512;

__device__ __forceinline__ void taps_of(const float* pseudo, int e,
                                        int& a00, int& a01, int& a10, int& a11,
                                        float& c00, float& c01, float& c10, float& c11) {
    float px = pseudo[2 * e] * (KK - 1);
    float py = pseudo[2 * e + 1] * (KK - 1);
    float kfx = floorf(px), kfy = floorf(py);
    float fx = px - kfx, fy = py - kfy;
    int k0x = min(max((int)kfx, 0), KK - 1);
    int k0y = min(max((int)kfy, 0), KK - 1);
    int k1x = min(k0x + 1, KK - 1), k1y = min(k0y + 1, KK - 1);
    a00 = k0x * KK + k0y; a01 = k0x * KK + k1y;
    a10 = k1x * KK + k0y; a11 = k1x * KK + k1y;
    float gx = 1.f - fx, gy = 1.f - fy;
    c00 = gx * gy; c01 = gx * fy; c10 = fx * gy; c11 = fx * fy;
}

// ---- conv1 scatter: per edge, scatter x[src]*coeff into tap-space S[dst, 25] ----
__global__ void conv1_scatter(const float* __restrict__ x, const float* __restrict__ pseudo,
                              const int* __restrict__ ei,
                              float* __restrict__ S, float* __restrict__ deg) {
    int e = blockIdx.x * blockDim.x + threadIdx.x;
    if (e >= E0) return;
    int srcn = ei[e], dstn = ei[E0 + e];
    int a00, a01, a10, a11; float c00, c01, c10, c11;
    taps_of(pseudo, e, a00, a01, a10, a11, c00, c01, c10, c11);
    float xv = x[srcn];
    float* Sr = S + dstn * 32;
    atomicAdd(&Sr[a00], c00 * xv);
    atomicAdd(&Sr[a01], c01 * xv);
    atomicAdd(&Sr[a10], c10 * xv);
    atomicAdd(&Sr[a11], c11 * xv);
    atomicAdd(&deg[dstn], 1.0f);
}

// ---- node1: h1[n,o] = ELU( (S[n,:] @ W1[:,o]) / deg + x[n]*root[o] + bias[o] ) ----
__global__ void node1(const float* __restrict__ x, const float* __restrict__ W1,
                      const float* __restrict__ root, const float* __restrict__ bias,
                      const float* __restrict__ deg, const float* __restrict__ S,
                      float* __restrict__ h1) {
    int idx = blockIdx.x * blockDim.x + threadIdx.x;
    if (idx >= N0 * C1) return;
    int n = idx >> 5, o = idx & 31;
    const float* Sr = S + n * 32;
    float acc = 0.f;
#pragma unroll
    for (int k = 0; k < 25; k++) acc += Sr[k] * W1[k * C1 + o];
    float v = acc / fmaxf(deg[n], 1.0f) + x[n] * root[o] + bias[o];
    h1[idx] = v > 0.f ? v : expm1f(v);
}

// ---- pool1: [100,28,28,32] -> [100,14,14,32] ----
__global__ void pool1(const float* __restrict__ h1, float* __restrict__ p1) {
    int idx = blockIdx.x * blockDim.x + threadIdx.x;
    if (idx >= N1 * C1) return;
    int o = idx & 31; int t = idx >> 5;
    int c = t % 14; int r = (t / 14) % 14; int b = t / 196;
    const float* base = h1 + (((b * 28 + 2 * r) * 28 + 2 * c) * C1 + o);
    float m = fmaxf(fmaxf(base[0], base[C1]),
                    fmaxf(base[28 * C1], base[28 * C1 + C1]));
    p1[idx] = m;
}

// ---- gemm_y: y[n, k, o] = sum_i p1[n,i] * W2[k,i,o].  [19600,32]@[32,1600] ----
// grid (5, 490), block 320: thread = col c (k,o), 40 rows per block.
__global__ void gemm_y(const float* __restrict__ p1, const float* __restrict__ W2,
                       float* __restrict__ y) {
    __shared__ float xs[40 * 32];
    int tid = threadIdx.x;
    int c = blockIdx.x * 320 + tid;       // 0..1599
    int k = c >> 6, o = c & 63;
    int n0 = blockIdx.y * 40;
    // cooperative load of 40 rows of p1 (1280 floats)
    for (int i = tid; i < 40 * 32; i += 320) xs[i] = p1[n0 * 32 + i];
    float wcol[32];
    const float* wp = W2 + k * (C1 * C2) + o;
#pragma unroll
    for (int i = 0; i < C1; i++) wcol[i] = wp[i * C2];
    __syncthreads();
    for (int r = 0; r < 40; r++) {
        const float* xr = xs + r * 32;
        float acc = 0.f;
#pragma unroll
        for (int i = 0; i < C1; i++) acc += xr[i] * wcol[i];
        y[(n0 + r) * 1600 + c] = acc;
    }
}

// ---- conv2 gather: per (edge, o): msg = sum_tap c_tap * y[src, a_tap, o] ----
__global__ void conv2_gather(const float* __restrict__ y, const float* __restrict__ pseudo,
                             const int* __restrict__ ei,
                             float* __restrict__ agg, float* __restrict__ deg) {
    int idx = blockIdx.x * blockDim.x + threadIdx.x;
    if (idx >= E1 * C2) return;
    int e = idx >> 6, o = idx & 63;
    int srcn = ei[e], dstn = ei[E1 + e];
    int a00, a01, a10, a11; float c00, c01, c10, c11;
    taps_of(pseudo, e, a00, a01, a10, a11, c00, c01, c10, c11);
    const float* yr = y + srcn * 1600 + o;
    float msg = c00 * yr[a00 * 64] + c01 * yr[a01 * 64] +
                c10 * yr[a10 * 64] + c11 * yr[a11 * 64];
    atomicAdd(&agg[dstn * C2 + o], msg);
    if (o == 0) atomicAdd(&deg[dstn], 1.0f);
}

// ---- conv2 fallback (R3 version) if workspace can't hold y ----
__global__ void conv2_edges(const float* __restrict__ p1, const float* __restrict__ pseudo,
                            const int* __restrict__ ei, const float* __restrict__ W2,
                            float* __restrict__ agg, float* __restrict__ deg) {
    int idx = blockIdx.x * blockDim.x + threadIdx.x;
    if (idx >= E1 * C2) return;
    int e = idx >> 6, o = idx & 63;
    int srcn = ei[e], dstn = ei[E1 + e];
    int a00, a01, a10, a11; float c00, c01, c10, c11;
    taps_of(pseudo, e, a00, a01, a10, a11, c00, c01, c10, c11);
    const float* w00 = W2 + a00 * C1 * C2 + o;
    const float* w01 = W2 + a01 * C1 * C2 + o;
    const float* w10 = W2 + a10 * C1 * C2 + o;
    const float* w11 = W2 + a11 * C1 * C2 + o;
    const float* xr = p1 + srcn * C1;
    float acc = 0.f;
#pragma unroll 8
    for (int i = 0; i < C1; i++) {
        float wi = c00 * w00[i * C2] + c01 * w01[i * C2] +
                   c10 * w10[i * C2] + c11 * w11[i * C2];
        acc += xr[i] * wi;
    }
    atomicAdd(&agg[dstn * C2 + o], acc);
    if (o == 0) atomicAdd(&deg[dstn], 1.0f);
}

// ---- node2: mean + x@root2 + bias + ELU, in-place over agg ----
__global__ void node2(const float* __restrict__ p1, const float* __restrict__ root2,
                      const float* __restrict__ bias, const float* __restrict__ deg,
                      float* __restrict__ agg) {
    int idx = blockIdx.x * blockDim.x + threadIdx.x;
    if (idx >= N1 * C2) return;
    int n = idx >> 6, o = idx & 63;
    float acc = agg[idx] / fmaxf(deg[n], 1.0f);
    const float* xr = p1 + n * C1;
#pragma unroll 8
    for (int i = 0; i < C1; i++) acc += xr[i] * root2[i * C2 + o];
    acc += bias[o];
    agg[idx] = acc > 0.f ? acc : expm1f(acc);
}

// ---- pool2: view [19600,64] as [25,28,28,64] -> [25,14,14,64] == [100,3136] ----
__global__ void pool2(const float* __restrict__ h2, float* __restrict__ p2) {
    int idx = blockIdx.x * blockDim.x + threadIdx.x;
    if (idx >= 25 * 14 * 14 * C2) return;
    int o = idx & 63; int t = idx >> 6;
    int c = t % 14; int r = (t / 14) % 14; int b = t / 196;
    const float* base = h2 + (((b * 28 + 2 * r) * 28 + 2 * c) * C2 + o);
    float m = fmaxf(fmaxf(base[0], base[C2]),
                    fmaxf(base[28 * C2], base[28 * C2 + C2]));
    p2[idx] = m;
}

// ---- fc1 split-K: grid (25 bgroups, 8 jtiles, 4 kz); block 256 = 64 j x 4 ks ----
__global__ void fc1_splitk(const float* __restrict__ p2, const float* __restrict__ w,
                           float* __restrict__ z1) {
    int bg = blockIdx.x;
    int jt = blockIdx.y;
    int kz = blockIdx.z;
    int t = threadIdx.x;
    int j = (jt << 6) + (t & 63);
    int ks = t >> 6;
    int k0 = kz * 784 + ks * 196;
    const float* x0 = p2 + (bg * 4 + 0) * FC1_IN;
    const float* x1 = p2 + (bg * 4 + 1) * FC1_IN;
    const float* x2 = p2 + (bg * 4 + 2) * FC1_IN;
    const float* x3 = p2 + (bg * 4 + 3) * FC1_IN;
    const float* wp = w + j;
    float a0 = 0.f, a1 = 0.f, a2 = 0.f, a3 = 0.f;
#pragma unroll 4
    for (int kk = 0; kk < 196; kk++) {
        int k = k0 + kk;
        float wv = wp[k * FC1_OUT];
        a0 += x0[k] * wv; a1 += x1[k] * wv;
        a2 += x2[k] * wv; a3 += x3[k] * wv;
    }
    atomicAdd(&z1[(bg * 4 + 0) * FC1_OUT + j], a0);
    atomicAdd(&z1[(bg * 4 + 1) * FC1_OUT + j], a1);
    atomicAdd(&z1[(bg * 4 + 2) * FC1_OUT + j], a2);
    atomicAdd(&z1[(bg * 4 + 3) * FC1_OUT + j], a3);
}

// ---- fc2 + log_softmax fused; applies fc1 bias+ELU inline. block=640 (10 waves) ----
__global__ void fc2_lsm(const float* __restrict__ z1, const float* __restrict__ fc1b,
                        const float* __restrict__ w, const float* __restrict__ fc2b,
                        float* __restrict__ out) {
    int b = blockIdx.x;
    int t = threadIdx.x;
    int wv = t >> 6;
    int lane = t & 63;
    const float* zr = z1 + b * 512;
    float acc = 0.f;
#pragma unroll
    for (int m = 0; m < 8; m++) {
        int k = lane * 8 + m;
        float xv = zr[k] + fc1b[k];
        xv = xv > 0.f ? xv : expm1f(xv);
        acc += xv * w[k * 10 + wv];
    }
#pragma unroll
    for (int off = 32; off > 0; off >>= 1) acc += __shfl_down(acc, off);
    __shared__ float zs[10];
    if (lane == 0) {
        float z = acc + fc2b[wv];
        zs[wv] = z > 0.f ? z : expm1f(z);
    }
    __syncthreads();
    if (t < 10) {
        float m = -1e30f;
        for (int jj = 0; jj < 10; jj++) m = fmaxf(m, zs[jj]);
        float s = 0.f;
        for (int jj = 0; jj < 10; jj++) s += expf(zs[jj] - m);
        out[b * 10 + t] = zs[t] - m - logf(s);
    }
}

extern "C" void kernel_launch(void* const* d_in, const int* in_sizes, int n_in,
                              void* d_out, int out_size, void* d_ws, size_t ws_size,
                              hipStream_t stream) {
    const float* x     = (const float*)d_in[0];
    const float* ps0   = (const float*)d_in[1];
    const float* ps1   = (const float*)d_in[2];
    const float* W1    = (const float*)d_in[3];
    const float* root1 = (const float*)d_in[4];
    const float* b1    = (const float*)d_in[5];
    const float* W2    = (const float*)d_in[6];
    const float* root2 = (const float*)d_in[7];
    const float* b2v   = (const float*)d_in[8];
    const float* fc1w  = (const float*)d_in[9];
    const float* fc1b  = (const float*)d_in[10];
    const float* fc2w  = (const float*)d_in[11];
    const float* fc2b  = (const float*)d_in[12];
    const int*   ei0   = (const int*)d_in[13];
    const int*   ei1   = (const int*)d_in[14];

    float* ws = (float*)d_ws;
    float* S1   = ws;                       // 2,508,800  (only 25/32 cols used)
    float* deg1 = ws + 2508800;             //    78,400
    float* agg2 = ws + 2587200;             // 1,254,400
    float* deg2 = ws + 3841600;             //    19,600
    float* z1   = ws + 3861200;             //    51,200
    // ---- memset boundary: 3,912,400 floats ----
    float* h1   = ws + 3912400;             // 2,508,800
    float* p1   = ws + 6421200;             //   627,200
    float* p2   = ws + 7048400;             //   313,600
    float* y    = ws + 7362000;             // 31,360,000
    // high water: 38,722,000 floats = 154.9 MB
    const size_t need = (size_t)38722000 * sizeof(float);

    hipMemsetAsync(ws, 0, (size_t)3912400 * sizeof(float), stream);

    conv1_scatter<<<(E0 + 255) / 256, 256, 0, stream>>>(x, ps0, ei0, S1, deg1);
    node1<<<(N0 * C1 + 255) / 256, 256, 0, stream>>>(x, W1, root1, b1, deg1, S1, h1);
    pool1<<<(N1 * C1 + 255) / 256, 256, 0, stream>>>(h1, p1);
    if (ws_size >= need) {
        gemm_y<<<dim3(5, 490), 320, 0, stream>>>(p1, W2, y);
        conv2_gather<<<(E1 * C2 + 255) / 256, 256, 0, stream>>>(y, ps1, ei1, agg2, deg2);
    } else {
        conv2_edges<<<(E1 * C2 + 255) / 256, 256, 0, stream>>>(p1, ps1, ei1, W2, agg2, deg2);
    }
    node2<<<(N1 * C2 + 255) / 256, 256, 0, stream>>>(p1, root2, b2v, deg2, agg2);
    pool2<<<(25 * 14 * 14 * C2 + 255) / 256, 256, 0, stream>>>(agg2, p2);
    fc1_splitk<<<dim3(25, 8, 4), 256, 0, stream>>>(p2, fc1w, z1);
    fc2_lsm<<<BSZ, 640, 0, stream>>>(z1, fc1b, fc2w, fc2b, (float*)d_out);
}